// Round 12
// baseline (271.039 us; speedup 1.0000x reference)
//
#include <hip/hip_runtime.h>

#define N_NODES 100000
#define NDUMMY 100000   // dummy zero row index (padded table row)
#define NH 64
#define NB 512          // buckets
#define NPB 196         // nodes per bucket (512*196 = 100352 >= N); 196%4==0
#define BCAP 4096       // raw bucket capacity (avg 3125, +17 sigma)
#define PBCAP 5760      // padded bucket region (group-of-4 padding)
#define EPB 4096        // edges per sort block -> 391 blocks

// ---------------- bf16 helpers ----------------

__device__ __forceinline__ unsigned short f2bf(float f) {
    union { float f; unsigned int i; } c;
    c.f = f;
    unsigned int b = c.i;
    b += 0x7FFFu + ((b >> 16) & 1u);   // round to nearest even
    return (unsigned short)(b >> 16);
}

__device__ __forceinline__ float bfLO(unsigned u) {
    union { unsigned i; float f; } c; c.i = u << 16; return c.f;
}
__device__ __forceinline__ float bfHI(unsigned u) {
    union { unsigned i; float f; } c; c.i = u & 0xFFFF0000u; return c.f;
}

// ---------------- init: zero bucket cursors + dummy hs row ----------------

__global__ __launch_bounds__(512) void k_init(int* __restrict__ bcur, unsigned* __restrict__ dummy_row) {
    int t = threadIdx.x;
    if (t < NB) bcur[t] = 0;
    if (t < 32) dummy_row[t] = 0;   // 128B bf16 row of zeros
}

// ---------------- CSR build via block-local counting sort ----------------
// 512 threads, 4096 edges/block -> 391 blocks. Dense flush runs avg 32B.

__global__ __launch_bounds__(512) void k_sort(const int* __restrict__ src, const int* __restrict__ dst,
                                              int* __restrict__ bcur, unsigned* __restrict__ ebuf, int e) {
    __shared__ unsigned sorted[EPB];        // 16KB
    __shared__ unsigned short cellof[EPB];  // 8KB
    __shared__ int lh[NB];
    __shared__ int lbase[NB];
    __shared__ int lcur[NB];
    __shared__ int gpos[NB];
    __shared__ int wsum[8];
    const int t = threadIdx.x;
    const int lane = t & 63, wave = t >> 6;
    const int e0 = blockIdx.x * EPB;
    int cnt = e - e0; if (cnt > EPB) cnt = EPB;

    lh[t] = 0;
    __syncthreads();

    for (int i = t; i < cnt; i += 512) {
        int d = dst[e0 + i];
        atomicAdd(&lh[d / NPB], 1);
    }
    __syncthreads();

    // scan: exactly 1 bucket per thread (NB == 512)
    const int v = lh[t];
    int inc = v;
#pragma unroll
    for (int d = 1; d < 64; d <<= 1) {
        int u = __shfl_up(inc, d, 64);
        if (lane >= d) inc += u;
    }
    if (lane == 63) wsum[wave] = inc;
    __syncthreads();
    int woff = 0;
#pragma unroll
    for (int w = 0; w < 8; ++w)
        if (w < wave) woff += wsum[w];
    const int excl = woff + inc - v;
    lbase[t] = excl;
    lcur[t] = excl;
    gpos[t] = atomicAdd(&bcur[t], v);
    __syncthreads();

    for (int i = t; i < cnt; i += 512) {
        int d = dst[e0 + i];
        int s = src[e0 + i];
        int b = d / NPB;
        int dl = d - b * NPB;
        int pos = atomicAdd(&lcur[b], 1);
        sorted[pos] = ((unsigned)dl << 17) | (unsigned)s;
        cellof[pos] = (unsigned short)b;
    }
    __syncthreads();

    for (int i = t; i < cnt; i += 512) {
        int c = cellof[i];
        int off = i - lbase[c];
        int gp = gpos[c] + off;
        if (gp < BCAP) ebuf[(long long)c * BCAP + gp] = sorted[i];
    }
}

// one block per bucket: stage region in LDS, hist; pad each aligned GROUP OF 4
// nodes to the group-max degree (mult of 8); scatter into fixed csrc region.
__global__ __launch_bounds__(256) void k_build(const unsigned* __restrict__ ebuf, const int* __restrict__ bcur,
                                               int* __restrict__ rowptr, int* __restrict__ degp,
                                               float* __restrict__ dinv, int* __restrict__ csrc, int n) {
    __shared__ unsigned ls[BCAP];
    __shared__ int lh[256];
    __shared__ int lpv[256];
    __shared__ int lstart[256];
    __shared__ int lc[256];
    __shared__ int wsum[4];
    const int b = blockIdx.x;
    const int t = threadIdx.x;
    const int node0 = b * NPB;
    int count = bcur[b];
    if (count > BCAP) count = BCAP;
    const int rbase = b * PBCAP;

    lh[t] = 0;
    for (int i = t; i < count; i += 256) ls[i] = ebuf[(long long)b * BCAP + i];
    __syncthreads();
    for (int i = t; i < count; i += 256) atomicAdd(&lh[ls[i] >> 17], 1);
    __syncthreads();

    const int v = lh[t];
    lpv[t] = (v + 7) & ~7;
    __syncthreads();
    const int g = t & ~3;
    const int pvg = max(max(lpv[g], lpv[g + 1]), max(lpv[g + 2], lpv[g + 3]));

    const int lane = t & 63, wave = t >> 6;
    int inc = pvg;
#pragma unroll
    for (int d = 1; d < 64; d <<= 1) {
        int u = __shfl_up(inc, d, 64);
        if (lane >= d) inc += u;
    }
    if (lane == 63) wsum[wave] = inc;
    __syncthreads();
    int woff = 0;
#pragma unroll
    for (int w = 0; w < 4; ++w)
        if (w < wave) woff += wsum[w];
    const int start = rbase + woff + inc - pvg;

    lstart[t] = start;
    lc[t] = start;
    const int node = node0 + t;
    if (t < NPB && node < n) {
        rowptr[node] = start;
        degp[node] = pvg;
        dinv[node] = rsqrtf((float)(v + 1));   // +1 self loop
    }
    __syncthreads();

    for (int i = t; i < count; i += 256) {
        unsigned u = ls[i];
        int pos = atomicAdd(&lc[u >> 17], 1);
        csrc[pos] = (int)(u & 0x1FFFFu);
    }
    __syncthreads();

    const int pend = lstart[t] + pvg;
    for (int p = lc[t]; p < pend; ++p) csrc[p] = NDUMMY;
}

// ---------------- GEMM: hs[node][c] = bf16( (sum_k X[node][k]*W[k][c]) * dinv[node] ) ----------
// No LDS. lane = column; W column in 128 VGPRs (L1-hot global loads);
// X rows wave-uniform -> scalar-cache s_load_dwordx4; inner loop = pure v_fmac.
// 8 nodes/wave, 256 threads = 32 nodes/block; N % 32 == 0 -> all blocks full.

template <int K>
__global__ __launch_bounds__(256) void k_gemm_scale(const float* __restrict__ X, const float* __restrict__ W,
                                                    const float* __restrict__ dinv,
                                                    unsigned short* __restrict__ out, int n) {
    const int lane = threadIdx.x & 63;
    const int wv = threadIdx.x >> 6;

    float wreg[K];
#pragma unroll
    for (int k = 0; k < K; ++k) wreg[k] = W[k * NH + lane];

    const int nb0 = __builtin_amdgcn_readfirstlane((blockIdx.x * 4 + wv) * 8);
    if (nb0 >= n) return;
    const float* xp = X + (long long)nb0 * K;

    float acc[8];
#pragma unroll
    for (int r = 0; r < 8; ++r) acc[r] = 0.f;

#pragma unroll
    for (int k0 = 0; k0 < K; k0 += 4) {
        float4 x0 = *(const float4*)&xp[0 * K + k0];
        float4 x1 = *(const float4*)&xp[1 * K + k0];
        float4 x2 = *(const float4*)&xp[2 * K + k0];
        float4 x3 = *(const float4*)&xp[3 * K + k0];
        float4 x4 = *(const float4*)&xp[4 * K + k0];
        float4 x5 = *(const float4*)&xp[5 * K + k0];
        float4 x6 = *(const float4*)&xp[6 * K + k0];
        float4 x7 = *(const float4*)&xp[7 * K + k0];
        acc[0] = fmaf(x0.x, wreg[k0], fmaf(x0.y, wreg[k0 + 1], fmaf(x0.z, wreg[k0 + 2], fmaf(x0.w, wreg[k0 + 3], acc[0]))));
        acc[1] = fmaf(x1.x, wreg[k0], fmaf(x1.y, wreg[k0 + 1], fmaf(x1.z, wreg[k0 + 2], fmaf(x1.w, wreg[k0 + 3], acc[1]))));
        acc[2] = fmaf(x2.x, wreg[k0], fmaf(x2.y, wreg[k0 + 1], fmaf(x2.z, wreg[k0 + 2], fmaf(x2.w, wreg[k0 + 3], acc[2]))));
        acc[3] = fmaf(x3.x, wreg[k0], fmaf(x3.y, wreg[k0 + 1], fmaf(x3.z, wreg[k0 + 2], fmaf(x3.w, wreg[k0 + 3], acc[3]))));
        acc[4] = fmaf(x4.x, wreg[k0], fmaf(x4.y, wreg[k0 + 1], fmaf(x4.z, wreg[k0 + 2], fmaf(x4.w, wreg[k0 + 3], acc[4]))));
        acc[5] = fmaf(x5.x, wreg[k0], fmaf(x5.y, wreg[k0 + 1], fmaf(x5.z, wreg[k0 + 2], fmaf(x5.w, wreg[k0 + 3], acc[5]))));
        acc[6] = fmaf(x6.x, wreg[k0], fmaf(x6.y, wreg[k0 + 1], fmaf(x6.z, wreg[k0 + 2], fmaf(x6.w, wreg[k0 + 3], acc[6]))));
        acc[7] = fmaf(x7.x, wreg[k0], fmaf(x7.y, wreg[k0 + 1], fmaf(x7.z, wreg[k0 + 2], fmaf(x7.w, wreg[k0 + 3], acc[7]))));
    }

#pragma unroll
    for (int r = 0; r < 8; ++r) {
        int node = nb0 + r;
        if (node < n) {
            float dv = dinv[node];
            out[(long long)node * NH + lane] = f2bf(acc[r] * dv);
        }
    }
}

// ---------------- aggregation: 4 nodes/wave, lane loads uint2 (4 bf16 features) ----------

__global__ __launch_bounds__(256) void k_agg(const unsigned* __restrict__ hs32, const float* __restrict__ dinv,
                                             const int* __restrict__ rowptr, const int* __restrict__ degp,
                                             const int* __restrict__ csrc,
                                             const float* __restrict__ bias, const float* __restrict__ resid,
                                             float* __restrict__ out, int n) {
    const int gt = blockIdx.x * 256 + threadIdx.x;
    const int wave = gt >> 6;
    const int lane = threadIdx.x & 63;
    const int sub = lane >> 4;              // node within wave (0..3)
    const int li = lane & 15;               // uint2 index within row
    const int node = wave * 4 + sub;
    if (node >= n) return;

    const uint2* hsv = (const uint2*)hs32;  // row = 16 uint2
    uint2 su = hsv[node * 16 + li];         // self loop
    float aLx = bfLO(su.x), aHx = bfHI(su.x), aLy = bfLO(su.y), aHy = bfHI(su.y);
    float bLx = 0.f, bHx = 0.f, bLy = 0.f, bHy = 0.f;

    const int rp = rowptr[node];
    const int dg = degp[node];              // same for all 4 nodes in group
    for (int e = 0; e < dg; e += 8) {
        int4 c0 = *(const int4*)&csrc[rp + e];
        int4 c1 = *(const int4*)&csrc[rp + e + 4];
        uint2 u0 = hsv[c0.x * 16 + li];
        uint2 u1 = hsv[c0.y * 16 + li];
        uint2 u2 = hsv[c0.z * 16 + li];
        uint2 u3 = hsv[c0.w * 16 + li];
        uint2 u4 = hsv[c1.x * 16 + li];
        uint2 u5 = hsv[c1.y * 16 + li];
        uint2 u6 = hsv[c1.z * 16 + li];
        uint2 u7 = hsv[c1.w * 16 + li];
        aLx += bfLO(u0.x); aHx += bfHI(u0.x); aLy += bfLO(u0.y); aHy += bfHI(u0.y);
        bLx += bfLO(u1.x); bHx += bfHI(u1.x); bLy += bfLO(u1.y); bHy += bfHI(u1.y);
        aLx += bfLO(u2.x); aHx += bfHI(u2.x); aLy += bfLO(u2.y); aHy += bfHI(u2.y);
        bLx += bfLO(u3.x); bHx += bfHI(u3.x); bLy += bfLO(u3.y); bHy += bfHI(u3.y);
        aLx += bfLO(u4.x); aHx += bfHI(u4.x); aLy += bfLO(u4.y); aHy += bfHI(u4.y);
        bLx += bfLO(u5.x); bHx += bfHI(u5.x); bLy += bfLO(u5.y); bHy += bfHI(u5.y);
        aLx += bfLO(u6.x); aHx += bfHI(u6.x); aLy += bfLO(u6.y); aHy += bfHI(u6.y);
        bLx += bfLO(u7.x); bHx += bfHI(u7.x); bLy += bfLO(u7.y); bHy += bfHI(u7.y);
    }
    const float dv = dinv[node];
    const float4 bb = *(const float4*)&bias[4 * li];
    float v0 = fmaxf(dv * (aLx + bLx) + bb.x, 0.f);
    float v1 = fmaxf(dv * (aHx + bHx) + bb.y, 0.f);
    float v2 = fmaxf(dv * (aLy + bLy) + bb.z, 0.f);
    float v3 = fmaxf(dv * (aHy + bHy) + bb.w, 0.f);
    const long long ob = (long long)node * NH + 4 * li;
    if (resid) {
        float4 rr = *(const float4*)&resid[ob];
        v0 += rr.x; v1 += rr.y; v2 += rr.z; v3 += rr.w;
    }
    *(float4*)&out[ob] = make_float4(v0, v1, v2, v3);
}

// ---------------- launch ----------------

extern "C" void kernel_launch(void* const* d_in, const int* in_sizes, int n_in,
                              void* d_out, int out_size, void* d_ws, size_t ws_size,
                              hipStream_t stream) {
    const float* x  = (const float*)d_in[0];
    const int*   ei = (const int*)d_in[1];
    const float* W1 = (const float*)d_in[2];
    const float* b1 = (const float*)d_in[3];
    const float* W2 = (const float*)d_in[4];
    const float* b2 = (const float*)d_in[5];
    float* out = (float*)d_out;

    const int N = N_NODES;
    const int E = in_sizes[1] / 2;
    const int* src = ei;
    const int* dst = ei + E;

    // workspace layout (element offsets, 16B-aligned). hsb aliases ebuf:
    // ebuf (8.4MB) is dead after k_build; gemm1 overwrites the region (stream-ordered).
    // Dummy row NDUMMY is beyond ebuf extent -> survives k_sort/k_build.
    const int NP = 100352;  // padded N (= NB*NPB)
    int*   bcur   = (int*)d_ws;                      // NB
    int*   rowptr = bcur + NB;                       // NP
    int*   degp   = rowptr + NP;                     // NP
    float* dinv   = (float*)(degp + NP);             // NP
    int*   csrc   = (int*)(dinv + NP);               // NB*PBCAP
    unsigned* ebuf = (unsigned*)(csrc + NB * PBCAP); // NB*BCAP u32 = 8.39MB
    unsigned* hs32 = ebuf;                           // packed bf16 [..][32] (aliases ebuf)
    unsigned short* hsb = (unsigned short*)hs32;
    float* h1     = (float*)(hs32 + (long long)(NDUMMY + 1) * 32);  // fp32 [N][64]

    const int nb_sort = (E + EPB - 1) / EPB;         // 391

    k_init<<<1, 512, 0, stream>>>(bcur, hs32 + (long long)NDUMMY * 32);
    k_sort<<<nb_sort, 512, 0, stream>>>(src, dst, bcur, ebuf, E);
    k_build<<<NB, 256, 0, stream>>>(ebuf, bcur, rowptr, degp, dinv, csrc, N);

    // layer 1
    k_gemm_scale<128><<<(N + 31) / 32, 256, 0, stream>>>(x, W1, dinv, hsb, N);
    k_agg<<<(N + 15) / 16, 256, 0, stream>>>(hs32, dinv, rowptr, degp, csrc, b1, nullptr, h1, N);

    // layer 2 (+ residual h1)
    k_gemm_scale<64><<<(N + 31) / 32, 256, 0, stream>>>(h1, W2, dinv, hsb, N);
    k_agg<<<(N + 15) / 16, 256, 0, stream>>>(hs32, dinv, rowptr, degp, csrc, b2, h1, out, N);
}

// Round 13
// 153.636 us; speedup vs baseline: 1.7642x; 1.7642x over previous
//
#include <hip/hip_runtime.h>

#define N_NODES 100000
#define NDUMMY 100000   // dummy zero row index (padded table row)
#define NH 64
#define NB 512          // buckets
#define NPB 196         // nodes per bucket (512*196 = 100352 >= N); 196%4==0
#define BCAP 4096       // raw bucket capacity (avg 3125, +17 sigma)
#define PBCAP 5760      // padded bucket region (group-of-4 padding)
#define EPB 8192        // edges per sort block -> 196 blocks, 1024 threads

// ---------------- bf16 helpers ----------------

__device__ __forceinline__ unsigned short f2bf(float f) {
    union { float f; unsigned int i; } c;
    c.f = f;
    unsigned int b = c.i;
    b += 0x7FFFu + ((b >> 16) & 1u);   // round to nearest even
    return (unsigned short)(b >> 16);
}

__device__ __forceinline__ unsigned pack2bf(float lo, float hi) {
    return (unsigned)f2bf(lo) | ((unsigned)f2bf(hi) << 16);
}

__device__ __forceinline__ float bfLO(unsigned u) {
    union { unsigned i; float f; } c; c.i = u << 16; return c.f;
}
__device__ __forceinline__ float bfHI(unsigned u) {
    union { unsigned i; float f; } c; c.i = u & 0xFFFF0000u; return c.f;
}

// ---------------- init: zero bucket cursors + dummy hs row ----------------

__global__ __launch_bounds__(512) void k_init(int* __restrict__ bcur, unsigned* __restrict__ dummy_row) {
    int t = threadIdx.x;
    if (t < NB) bcur[t] = 0;
    if (t < 32) dummy_row[t] = 0;   // 128B bf16 row of zeros
}

// ---------------- CSR build via block-local counting sort ----------------
// 1024 threads, 8192 edges/block (int4 loads: 4x ILP on the atomic chains).
// Flush runs avg 16 edges = 64B -> ~1x write amplification.

__global__ __launch_bounds__(1024) void k_sort(const int* __restrict__ src, const int* __restrict__ dst,
                                               int* __restrict__ bcur, unsigned* __restrict__ ebuf, int e) {
    __shared__ unsigned sorted[EPB];        // 32KB
    __shared__ unsigned short cellof[EPB];  // 16KB
    __shared__ int lh[NB];
    __shared__ int lbase[NB];
    __shared__ int lcur[NB];
    __shared__ int gpos[NB];
    __shared__ int wsum[8];
    const int t = threadIdx.x;
    const int e0 = blockIdx.x * EPB;
    int cnt = e - e0; if (cnt > EPB) cnt = EPB;   // multiple of 4 (E%4==0)

    if (t < NB) lh[t] = 0;
    __syncthreads();

    // A: histogram (int4 loads, 4 independent atomic chains)
    for (int i = t * 4; i < cnt; i += 4096) {
        int4 d4 = *(const int4*)&dst[e0 + i];
        atomicAdd(&lh[d4.x / NPB], 1);
        atomicAdd(&lh[d4.y / NPB], 1);
        atomicAdd(&lh[d4.z / NPB], 1);
        atomicAdd(&lh[d4.w / NPB], 1);
    }
    __syncthreads();

    // B: scan over 512 buckets (threads 0..511) + global claims
    const int lane = t & 63, wave = t >> 6;
    int v = 0, inc = 0;
    if (t < NB) {
        v = lh[t];
        inc = v;
#pragma unroll
        for (int d = 1; d < 64; d <<= 1) {
            int u = __shfl_up(inc, d, 64);
            if (lane >= d) inc += u;
        }
        if (lane == 63) wsum[wave] = inc;
    }
    __syncthreads();
    if (t < NB) {
        int woff = 0;
#pragma unroll
        for (int w = 0; w < 8; ++w)
            if (w < wave) woff += wsum[w];
        const int excl = woff + inc - v;
        lbase[t] = excl;
        lcur[t] = excl;
        gpos[t] = atomicAdd(&bcur[t], v);
    }
    __syncthreads();

    // C: counting sort into LDS (int4 re-reads, L2-hot)
    for (int i = t * 4; i < cnt; i += 4096) {
        int4 d4 = *(const int4*)&dst[e0 + i];
        int4 s4 = *(const int4*)&src[e0 + i];
        int b0 = d4.x / NPB, b1 = d4.y / NPB, b2 = d4.z / NPB, b3 = d4.w / NPB;
        int p0 = atomicAdd(&lcur[b0], 1);
        int p1 = atomicAdd(&lcur[b1], 1);
        int p2 = atomicAdd(&lcur[b2], 1);
        int p3 = atomicAdd(&lcur[b3], 1);
        sorted[p0] = ((unsigned)(d4.x - b0 * NPB) << 17) | (unsigned)s4.x; cellof[p0] = (unsigned short)b0;
        sorted[p1] = ((unsigned)(d4.y - b1 * NPB) << 17) | (unsigned)s4.y; cellof[p1] = (unsigned short)b1;
        sorted[p2] = ((unsigned)(d4.z - b2 * NPB) << 17) | (unsigned)s4.z; cellof[p2] = (unsigned short)b2;
        sorted[p3] = ((unsigned)(d4.w - b3 * NPB) << 17) | (unsigned)s4.w; cellof[p3] = (unsigned short)b3;
    }
    __syncthreads();

    // D: dense flush (b128 LDS reads; consecutive lanes -> consecutive addresses)
    for (int i = t * 4; i < cnt; i += 4096) {
        uint4 sv = *(const uint4*)&sorted[i];
        ushort4 cv = *(const ushort4*)&cellof[i];
        int c0 = cv.x, c1 = cv.y, c2 = cv.z, c3 = cv.w;
        int g0 = gpos[c0] + (i + 0 - lbase[c0]);
        int g1 = gpos[c1] + (i + 1 - lbase[c1]);
        int g2 = gpos[c2] + (i + 2 - lbase[c2]);
        int g3 = gpos[c3] + (i + 3 - lbase[c3]);
        if (g0 < BCAP) ebuf[(long long)c0 * BCAP + g0] = sv.x;
        if (g1 < BCAP) ebuf[(long long)c1 * BCAP + g1] = sv.y;
        if (g2 < BCAP) ebuf[(long long)c2 * BCAP + g2] = sv.z;
        if (g3 < BCAP) ebuf[(long long)c3 * BCAP + g3] = sv.w;
    }
}

// one block per bucket: stage region in LDS, hist; pad each aligned GROUP OF 4
// nodes to the group-max degree (mult of 8); scatter into fixed csrc region.
__global__ __launch_bounds__(256) void k_build(const unsigned* __restrict__ ebuf, const int* __restrict__ bcur,
                                               int* __restrict__ rowptr, int* __restrict__ degp,
                                               float* __restrict__ dinv, int* __restrict__ csrc, int n) {
    __shared__ unsigned ls[BCAP];
    __shared__ int lh[256];
    __shared__ int lpv[256];
    __shared__ int lstart[256];
    __shared__ int lc[256];
    __shared__ int wsum[4];
    const int b = blockIdx.x;
    const int t = threadIdx.x;
    const int node0 = b * NPB;
    int count = bcur[b];
    if (count > BCAP) count = BCAP;
    const int rbase = b * PBCAP;

    lh[t] = 0;
    for (int i = t; i < count; i += 256) ls[i] = ebuf[(long long)b * BCAP + i];
    __syncthreads();
    for (int i = t; i < count; i += 256) atomicAdd(&lh[ls[i] >> 17], 1);
    __syncthreads();

    const int v = lh[t];
    lpv[t] = (v + 7) & ~7;
    __syncthreads();
    const int g = t & ~3;
    const int pvg = max(max(lpv[g], lpv[g + 1]), max(lpv[g + 2], lpv[g + 3]));

    const int lane = t & 63, wave = t >> 6;
    int inc = pvg;
#pragma unroll
    for (int d = 1; d < 64; d <<= 1) {
        int u = __shfl_up(inc, d, 64);
        if (lane >= d) inc += u;
    }
    if (lane == 63) wsum[wave] = inc;
    __syncthreads();
    int woff = 0;
#pragma unroll
    for (int w = 0; w < 4; ++w)
        if (w < wave) woff += wsum[w];
    const int start = rbase + woff + inc - pvg;

    lstart[t] = start;
    lc[t] = start;
    const int node = node0 + t;
    if (t < NPB && node < n) {
        rowptr[node] = start;
        degp[node] = pvg;
        dinv[node] = rsqrtf((float)(v + 1));   // +1 self loop
    }
    __syncthreads();

    for (int i = t; i < count; i += 256) {
        unsigned u = ls[i];
        int pos = atomicAdd(&lc[u >> 17], 1);
        csrc[pos] = (int)(u & 0x1FFFFu);
    }
    __syncthreads();

    const int pend = lstart[t] + pvg;
    for (int p = lc[t]; p < pend; ++p) csrc[p] = NDUMMY;
}

// ---------------- GEMM: hs[node][c] = bf16( (sum_k X[node][k]*W[k][c]) * dinv[node] ) ----------
// 256 threads, tile 64 nodes x 64 cols, thread tile 4x4, K-panel 64.
// xsT stored transposed [k][node] (pad 68 keeps 16B alignment): inner k-step is
// 2x ds_read_b128 (24cyc) vs 16 v_fmac (32cyc issue) -> VALU-bound.
// LDS 33.4KB -> 4 blocks/CU (16 waves/CU).

template <int K>
__global__ __launch_bounds__(256) void k_gemm_scale(const float* __restrict__ X, const float* __restrict__ W,
                                                    const float* __restrict__ dinv,
                                                    unsigned short* __restrict__ out, int n) {
    __shared__ float xsT[64][68];   // [k][node], 17.4KB
    __shared__ float ws[64][64];    // [k][col], 16.4KB
    const int tid = threadIdx.x;
    const int n0 = blockIdx.x * 64;
    const int tc = tid & 15;        // col group (4 cols)
    const int tn = tid >> 4;        // node group (4 nodes)

    float acc[4][4];
#pragma unroll
    for (int r = 0; r < 4; ++r)
#pragma unroll
        for (int c = 0; c < 4; ++c) acc[r][c] = 0.f;

    for (int kb = 0; kb < K; kb += 64) {
        // stage W panel (coalesced)
        for (int idx = tid * 4; idx < 4096; idx += 1024) {
            int r = idx >> 6, c = idx & 63;
            *(float4*)&ws[r][c] = *(const float4*)&W[(kb + r) * NH + c];
        }
        // stage X panel transposed (global coalesced: 16 lanes cover one row's 64 k)
        for (int idx = tid * 4; idx < 4096; idx += 1024) {
            int row = idx >> 6, c = idx & 63;
            float4 v = make_float4(0.f, 0.f, 0.f, 0.f);
            if (n0 + row < n) v = *(const float4*)&X[(long long)(n0 + row) * K + kb + c];
            xsT[c + 0][row] = v.x;
            xsT[c + 1][row] = v.y;
            xsT[c + 2][row] = v.z;
            xsT[c + 3][row] = v.w;
        }
        __syncthreads();

#pragma unroll 8
        for (int k = 0; k < 64; ++k) {
            float4 xa = *(const float4*)&xsT[k][tn * 4];
            float4 wa = *(const float4*)&ws[k][tc * 4];
            float xr[4] = {xa.x, xa.y, xa.z, xa.w};
            float wc[4] = {wa.x, wa.y, wa.z, wa.w};
#pragma unroll
            for (int r = 0; r < 4; ++r)
#pragma unroll
                for (int c = 0; c < 4; ++c) acc[r][c] += xr[r] * wc[c];
        }
        __syncthreads();
    }

#pragma unroll
    for (int r = 0; r < 4; ++r) {
        int node = n0 + 4 * tn + r;
        if (node < n) {
            float dv = dinv[node];
            ushort4 o;
            o.x = f2bf(acc[r][0] * dv);
            o.y = f2bf(acc[r][1] * dv);
            o.z = f2bf(acc[r][2] * dv);
            o.w = f2bf(acc[r][3] * dv);
            *(ushort4*)&out[(long long)node * NH + tc * 4] = o;
        }
    }
}

// ---------------- aggregation: 4 nodes/wave, lane loads uint2 (4 bf16 features) ----------

__global__ __launch_bounds__(256) void k_agg(const unsigned* __restrict__ hs32, const float* __restrict__ dinv,
                                             const int* __restrict__ rowptr, const int* __restrict__ degp,
                                             const int* __restrict__ csrc,
                                             const float* __restrict__ bias, const float* __restrict__ resid,
                                             float* __restrict__ out, int n) {
    const int gt = blockIdx.x * 256 + threadIdx.x;
    const int wave = gt >> 6;
    const int lane = threadIdx.x & 63;
    const int sub = lane >> 4;              // node within wave (0..3)
    const int li = lane & 15;               // uint2 index within row
    const int node = wave * 4 + sub;
    if (node >= n) return;

    const uint2* hsv = (const uint2*)hs32;  // row = 16 uint2
    uint2 su = hsv[node * 16 + li];         // self loop
    float aLx = bfLO(su.x), aHx = bfHI(su.x), aLy = bfLO(su.y), aHy = bfHI(su.y);
    float bLx = 0.f, bHx = 0.f, bLy = 0.f, bHy = 0.f;

    const int rp = rowptr[node];
    const int dg = degp[node];              // same for all 4 nodes in group
    for (int e = 0; e < dg; e += 8) {
        int4 c0 = *(const int4*)&csrc[rp + e];
        int4 c1 = *(const int4*)&csrc[rp + e + 4];
        uint2 u0 = hsv[c0.x * 16 + li];
        uint2 u1 = hsv[c0.y * 16 + li];
        uint2 u2 = hsv[c0.z * 16 + li];
        uint2 u3 = hsv[c0.w * 16 + li];
        uint2 u4 = hsv[c1.x * 16 + li];
        uint2 u5 = hsv[c1.y * 16 + li];
        uint2 u6 = hsv[c1.z * 16 + li];
        uint2 u7 = hsv[c1.w * 16 + li];
        aLx += bfLO(u0.x); aHx += bfHI(u0.x); aLy += bfLO(u0.y); aHy += bfHI(u0.y);
        bLx += bfLO(u1.x); bHx += bfHI(u1.x); bLy += bfLO(u1.y); bHy += bfHI(u1.y);
        aLx += bfLO(u2.x); aHx += bfHI(u2.x); aLy += bfLO(u2.y); aHy += bfHI(u2.y);
        bLx += bfLO(u3.x); bHx += bfHI(u3.x); bLy += bfLO(u3.y); bHy += bfHI(u3.y);
        aLx += bfLO(u4.x); aHx += bfHI(u4.x); aLy += bfLO(u4.y); aHy += bfHI(u4.y);
        bLx += bfLO(u5.x); bHx += bfHI(u5.x); bLy += bfLO(u5.y); bHy += bfHI(u5.y);
        aLx += bfLO(u6.x); aHx += bfHI(u6.x); aLy += bfLO(u6.y); aHy += bfHI(u6.y);
        bLx += bfLO(u7.x); bHx += bfHI(u7.x); bLy += bfLO(u7.y); bHy += bfHI(u7.y);
    }
    const float dv = dinv[node];
    const float4 bb = *(const float4*)&bias[4 * li];
    float v0 = fmaxf(dv * (aLx + bLx) + bb.x, 0.f);
    float v1 = fmaxf(dv * (aHx + bHx) + bb.y, 0.f);
    float v2 = fmaxf(dv * (aLy + bLy) + bb.z, 0.f);
    float v3 = fmaxf(dv * (aHy + bHy) + bb.w, 0.f);
    const long long ob = (long long)node * NH + 4 * li;
    if (resid) {
        float4 rr = *(const float4*)&resid[ob];
        v0 += rr.x; v1 += rr.y; v2 += rr.z; v3 += rr.w;
    }
    *(float4*)&out[ob] = make_float4(v0, v1, v2, v3);
}

// ---------------- launch ----------------

extern "C" void kernel_launch(void* const* d_in, const int* in_sizes, int n_in,
                              void* d_out, int out_size, void* d_ws, size_t ws_size,
                              hipStream_t stream) {
    const float* x  = (const float*)d_in[0];
    const int*   ei = (const int*)d_in[1];
    const float* W1 = (const float*)d_in[2];
    const float* b1 = (const float*)d_in[3];
    const float* W2 = (const float*)d_in[4];
    const float* b2 = (const float*)d_in[5];
    float* out = (float*)d_out;

    const int N = N_NODES;
    const int E = in_sizes[1] / 2;
    const int* src = ei;
    const int* dst = ei + E;

    // workspace layout (element offsets, 16B-aligned). hsb aliases ebuf:
    // ebuf (8.4MB) is dead after k_build; gemm1 overwrites the region (stream-ordered).
    // Dummy row NDUMMY is beyond ebuf extent -> survives k_sort/k_build.
    const int NP = 100352;  // padded N (= NB*NPB)
    int*   bcur   = (int*)d_ws;                      // NB
    int*   rowptr = bcur + NB;                       // NP
    int*   degp   = rowptr + NP;                     // NP
    float* dinv   = (float*)(degp + NP);             // NP
    int*   csrc   = (int*)(dinv + NP);               // NB*PBCAP
    unsigned* ebuf = (unsigned*)(csrc + NB * PBCAP); // NB*BCAP u32 = 8.39MB
    unsigned* hs32 = ebuf;                           // packed bf16 [..][32] (aliases ebuf)
    unsigned short* hsb = (unsigned short*)hs32;
    float* h1     = (float*)(hs32 + (long long)(NDUMMY + 1) * 32);  // fp32 [N][64]

    const int nb_sort = (E + EPB - 1) / EPB;         // 196

    k_init<<<1, 512, 0, stream>>>(bcur, hs32 + (long long)NDUMMY * 32);
    k_sort<<<nb_sort, 1024, 0, stream>>>(src, dst, bcur, ebuf, E);
    k_build<<<NB, 256, 0, stream>>>(ebuf, bcur, rowptr, degp, dinv, csrc, N);

    // layer 1
    k_gemm_scale<128><<<(N + 63) / 64, 256, 0, stream>>>(x, W1, dinv, hsb, N);
    k_agg<<<(N + 15) / 16, 256, 0, stream>>>(hs32, dinv, rowptr, degp, csrc, b1, nullptr, h1, N);

    // layer 2 (+ residual h1)
    k_gemm_scale<64><<<(N + 63) / 64, 256, 0, stream>>>(h1, W2, dinv, hsb, N);
    k_agg<<<(N + 15) / 16, 256, 0, stream>>>(hs32, dinv, rowptr, degp, csrc, b2, h1, out, N);
}